// Round 2
// baseline (366.623 us; speedup 1.0000x reference)
//
#include <hip/hip_runtime.h>
#include <cstdint>

typedef unsigned short u16;
typedef short bf16x8 __attribute__((ext_vector_type(8)));
typedef float f32x4 __attribute__((ext_vector_type(4)));

__device__ __forceinline__ u16 f2bf(float f) {
  unsigned u = __builtin_bit_cast(unsigned, f);
  u = (u + 0x7fffu + ((u >> 16) & 1u)) >> 16;
  return (u16)u;
}

// async global->LDS, 16B per lane. LDS dst = wave-uniform base (HW adds lane*16);
// global src is per-lane. Proper addrspacecast (no flat-address truncation).
__device__ __forceinline__ void gload_lds16(const void* g, void* l) {
  __builtin_amdgcn_global_load_lds(
      (const __attribute__((address_space(1))) unsigned int*)g,
      (__attribute__((address_space(3))) unsigned int*)l, 16, 0, 0);
}

// ---------------- Kernel 0: fp32 -> bf16 elementwise ------------------------
__global__ void cvt_f32_bf16(const float* __restrict__ src, u16* __restrict__ dst, int n4) {
  int i = blockIdx.x * 256 + threadIdx.x;
  if (i < n4) {
    float4 v = *reinterpret_cast<const float4*>(src + (size_t)i * 4);
    u16* d = dst + (size_t)i * 4;
    d[0] = f2bf(v.x); d[1] = f2bf(v.y); d[2] = f2bf(v.z); d[3] = f2bf(v.w);
  }
}

// ---------------- Kernel 1: weight transpose (fp32 in, bf16 out) ------------
// Wq/Wk/Wv: [16][1024][64] f32 -> Wt: [3072][1024] bf16 (row n = p*1024+h*64+d, col e)
__global__ void transpose_w_kernel(const float* __restrict__ Wq, const float* __restrict__ Wk,
                                   const float* __restrict__ Wv, u16* __restrict__ Wt) {
  __shared__ u16 tile[64][72];
  const int bid = blockIdx.x;
  const int et = bid & 15;         // e-tile of 64
  const int h  = (bid >> 4) & 15;
  const int p  = bid >> 8;         // 0=q 1=k 2=v
  const float* W = (p == 0) ? Wq : ((p == 1) ? Wk : Wv);
  const int tid = threadIdx.x;
  for (int idx = tid; idx < 4096; idx += 256) {
    int i = idx >> 6, d = idx & 63;                 // lanes sweep d -> coalesced read
    tile[d][i] = f2bf(W[(size_t)(h * 1024 + et * 64 + i) * 64 + d]);
  }
  __syncthreads();
  for (int idx = tid; idx < 4096; idx += 256) {
    int dd = idx >> 6, i = idx & 63;                // lanes sweep e -> coalesced write
    Wt[(size_t)(p * 1024 + h * 64 + dd) * 1024 + et * 64 + i] = tile[dd][i];
  }
}

// ---------------- Kernel 2/4: GEMM  C[M,N] = A[M,K] * Bt[N,K]^T -------------
// 128x128 tile, BK=64, 4 waves (2x2), each wave 64x64 = 4x4 MFMA frags.
// MODE 0: QKV epilogue (N=3072): n -> (proj,h,d); Q,K -> [B,H,T,64] bf16, V -> [B,H,64,T] bf16
// MODE 1: out-proj epilogue (N=1024): fp32 out += fp32 bias, store [M,N]
template <int N, int MODE>
__global__ __launch_bounds__(256, 2)
void gemm_bt(const u16* __restrict__ A, const u16* __restrict__ Bt,
             u16* __restrict__ O0, u16* __restrict__ O1, u16* __restrict__ O2,
             float* __restrict__ Of, const float* __restrict__ bias) {
  constexpr int K = 1024, BM = 128, BK = 64;
  __shared__ u16 Asm[BM * BK];
  __shared__ u16 Bsm[BM * BK];
  const int tid = threadIdx.x;
  const int lane = tid & 63;
  const int wid = tid >> 6;
  constexpr int nbn = N / 128;
  const int bid = blockIdx.x;
  const int m0 = (bid / nbn) * 128, n0 = (bid % nbn) * 128;
  const int wm = (wid >> 1) * 64, wn = (wid & 1) * 64;
  const int fr = lane & 15;
  const int fk = (lane >> 4) << 3;

  f32x4 acc[4][4];
#pragma unroll
  for (int i = 0; i < 4; ++i)
#pragma unroll
    for (int j = 0; j < 4; ++j) acc[i][j] = f32x4{0.f, 0.f, 0.f, 0.f};

  for (int k0 = 0; k0 < K; k0 += BK) {
#pragma unroll
    for (int i = 0; i < 4; ++i) {
      int cbase = i * 256 + wid * 64;          // wave-uniform chunk base
      int chunk = cbase + lane;                // per-lane chunk (16B)
      int row = chunk >> 3;                    // 8 chunks per 128B row
      int cole = (chunk & 7) << 3;             // col in bf16 elems
      gload_lds16(A + (size_t)(m0 + row) * K + k0 + cole, (char*)Asm + cbase * 16);
      gload_lds16(Bt + (size_t)(n0 + row) * K + k0 + cole, (char*)Bsm + cbase * 16);
    }
    __syncthreads();
#pragma unroll
    for (int kk = 0; kk < 2; ++kk) {
      bf16x8 af[4], bf[4];
#pragma unroll
      for (int mi = 0; mi < 4; ++mi)
        af[mi] = *reinterpret_cast<const bf16x8*>(&Asm[(wm + mi * 16 + fr) * BK + kk * 32 + fk]);
#pragma unroll
      for (int ni = 0; ni < 4; ++ni)
        bf[ni] = *reinterpret_cast<const bf16x8*>(&Bsm[(wn + ni * 16 + fr) * BK + kk * 32 + fk]);
#pragma unroll
      for (int mi = 0; mi < 4; ++mi)
#pragma unroll
        for (int ni = 0; ni < 4; ++ni)
          acc[mi][ni] = __builtin_amdgcn_mfma_f32_16x16x32_bf16(af[mi], bf[ni], acc[mi][ni], 0, 0, 0);
    }
    __syncthreads();
  }

  const int rq = (lane >> 4) << 2;  // C/D: col = lane&15, row = (lane>>4)*4 + reg
  if constexpr (MODE == 0) {
#pragma unroll
    for (int ni = 0; ni < 4; ++ni) {
      int n = n0 + wn + ni * 16 + fr;
      int pr = n >> 10, hh = (n >> 6) & 15, d = n & 63;
#pragma unroll
      for (int mi = 0; mi < 4; ++mi)
#pragma unroll
        for (int r = 0; r < 4; ++r) {
          int m = m0 + wm + mi * 16 + rq + r;
          int b = m >> 10, t = m & 1023;
          u16 val = f2bf(acc[mi][ni][r]);
          size_t bh = (size_t)(b * 16 + hh);
          if (pr == 0)      O0[(bh * 1024 + t) * 64 + d] = val;       // Q [B,H,T,64]
          else if (pr == 1) O1[(bh * 1024 + t) * 64 + d] = val;       // K [B,H,T,64]
          else              O2[(bh * 64 + d) * 1024 + t] = val;       // V^T [B,H,64,T]
        }
    }
  } else {
#pragma unroll
    for (int ni = 0; ni < 4; ++ni) {
      int n = n0 + wn + ni * 16 + fr;
      float bv = bias[n];
#pragma unroll
      for (int mi = 0; mi < 4; ++mi)
#pragma unroll
        for (int r = 0; r < 4; ++r) {
          int m = m0 + wm + mi * 16 + rq + r;
          Of[(size_t)m * N + n] = acc[mi][ni][r] + bv;
        }
    }
  }
}

// ---------------- Kernel 3: causal flash attention ---------------------------
// Q,K: [B*H][1024][64] bf16, V: [B*H][64][1024] bf16, O: [B][1024][1024] bf16
// block = 4 waves; wave w owns 16 q-rows; loop 64-wide KV tiles with online softmax.
__global__ __launch_bounds__(256, 2)
void attn_fwd(const u16* __restrict__ Q, const u16* __restrict__ K,
              const u16* __restrict__ V, u16* __restrict__ O) {
  __shared__ u16 Pl[4][1024];  // per-wave 16x64 bf16 P tile (XOR-swizzled)
  const int tid = threadIdx.x, lane = tid & 63, w = tid >> 6;
  const int bid = blockIdx.x;
  const int qc = bid & 15;        // q chunk of 64
  const int bh = bid >> 4;
  const int b = bh >> 4, h = bh & 15;
  const int q0 = qc * 64 + w * 16;
  const int fr = lane & 15, fg = lane >> 4, fk = fg << 3;
  const u16* Qb = Q + (size_t)bh * 65536;
  const u16* Kb = K + (size_t)bh * 65536;
  const u16* Vb = V + (size_t)bh * 65536;
  char* Pw = (char*)&Pl[w][0];

  bf16x8 qf[2];
  qf[0] = *reinterpret_cast<const bf16x8*>(&Qb[(q0 + fr) * 64 + fk]);
  qf[1] = *reinterpret_cast<const bf16x8*>(&Qb[(q0 + fr) * 64 + 32 + fk]);

  f32x4 o[4];
#pragma unroll
  for (int i = 0; i < 4; ++i) o[i] = f32x4{0.f, 0.f, 0.f, 0.f};
  float mrow[4] = {-1e30f, -1e30f, -1e30f, -1e30f};
  float lrow[4] = {0.f, 0.f, 0.f, 0.f};
  const float c = 0.125f * 1.44269504088896f;  // head_size^-0.5 * log2(e)

  for (int st = 0; st <= qc; ++st) {
    const u16* Kt = Kb + st * 4096;
    f32x4 s[4];
#pragma unroll
    for (int i = 0; i < 4; ++i) s[i] = f32x4{0.f, 0.f, 0.f, 0.f};
#pragma unroll
    for (int kk = 0; kk < 2; ++kk)
#pragma unroll
      for (int nf = 0; nf < 4; ++nf) {
        bf16x8 kf = *reinterpret_cast<const bf16x8*>(&Kt[(nf * 16 + fr) * 64 + kk * 32 + fk]);
        s[nf] = __builtin_amdgcn_mfma_f32_16x16x32_bf16(qf[kk], kf, s[nf], 0, 0, 0);
      }
    float sv[4][4];
    const bool diag = (st == qc);
#pragma unroll
    for (int nf = 0; nf < 4; ++nf)
#pragma unroll
      for (int r = 0; r < 4; ++r) {
        float xv = s[nf][r] * c;
        if (diag) {
          int sc = st * 64 + nf * 16 + fr;
          int qr = q0 + fg * 4 + r;
          if (sc > qr) xv = -1e30f;
        }
        sv[nf][r] = xv;
      }
    float mnew[4];
#pragma unroll
    for (int r = 0; r < 4; ++r) {
      float mx = fmaxf(fmaxf(sv[0][r], sv[1][r]), fmaxf(sv[2][r], sv[3][r]));
      mx = fmaxf(mx, __shfl_xor(mx, 1));
      mx = fmaxf(mx, __shfl_xor(mx, 2));
      mx = fmaxf(mx, __shfl_xor(mx, 4));
      mx = fmaxf(mx, __shfl_xor(mx, 8));
      mnew[r] = fmaxf(mrow[r], mx);
      float a = exp2f(mrow[r] - mnew[r]);
      lrow[r] *= a;
      o[0][r] *= a; o[1][r] *= a; o[2][r] *= a; o[3][r] *= a;
      mrow[r] = mnew[r];
    }
#pragma unroll
    for (int r = 0; r < 4; ++r) {
      float sum = 0.f;
#pragma unroll
      for (int nf = 0; nf < 4; ++nf) {
        float pv = exp2f(sv[nf][r] - mnew[r]);
        sum += pv;
        int mm = fg * 4 + r, nn = nf * 16 + fr;
        int byteoff = (mm * 128 + nn * 2) ^ ((mm & 7) << 4);
        *(u16*)(Pw + byteoff) = f2bf(pv);
      }
      sum += __shfl_xor(sum, 1);
      sum += __shfl_xor(sum, 2);
      sum += __shfl_xor(sum, 4);
      sum += __shfl_xor(sum, 8);
      lrow[r] += sum;
    }
    __syncthreads();
#pragma unroll
    for (int kk = 0; kk < 2; ++kk) {
      int rb = (fr * 128 + kk * 64 + fg * 16) ^ ((fr & 7) << 4);
      bf16x8 pa = *reinterpret_cast<const bf16x8*>(Pw + rb);
#pragma unroll
      for (int df = 0; df < 4; ++df) {
        bf16x8 vf = *reinterpret_cast<const bf16x8*>(&Vb[(df * 16 + fr) * 1024 + st * 64 + kk * 32 + fk]);
        o[df] = __builtin_amdgcn_mfma_f32_16x16x32_bf16(pa, vf, o[df], 0, 0, 0);
      }
    }
    __syncthreads();
  }

#pragma unroll
  for (int r = 0; r < 4; ++r) {
    float inv = 1.0f / lrow[r];
    int t = q0 + fg * 4 + r;
    size_t base = ((size_t)b * 1024 + t) * 1024 + h * 64;
#pragma unroll
    for (int df = 0; df < 4; ++df) O[base + df * 16 + fr] = f2bf(o[df][r] * inv);
  }
}

// ---------------- launcher ---------------------------------------------------
extern "C" void kernel_launch(void* const* d_in, const int* in_sizes, int n_in,
                              void* d_out, int out_size, void* d_ws, size_t ws_size,
                              hipStream_t stream) {
  (void)in_sizes; (void)n_in; (void)out_size; (void)ws_size;
  const float* x  = (const float*)d_in[0];
  const float* Wq = (const float*)d_in[1];
  const float* Wk = (const float*)d_in[2];
  const float* Wv = (const float*)d_in[3];
  const float* Wp = (const float*)d_in[4];
  const float* bp = (const float*)d_in[5];
  float* out = (float*)d_out;

  char* ws = (char*)d_ws;
  // region A (16MB): xb (bf16 x) for QKV GEMM, then reused as Ob (attn out, bf16)
  u16* xb  = (u16*)(ws);
  u16* Ob  = (u16*)(ws);
  // region B (6MB): Wt (bf16 QKV weights^T), then reused as Wpb (bf16 Wp)
  u16* Wt  = (u16*)(ws + 16777216);
  u16* Wpb = (u16*)(ws + 16777216);
  u16* Qb  = (u16*)(ws + 23068672);   // 16 MB: [B,H,1024,64]
  u16* Kb  = (u16*)(ws + 39845888);   // 16 MB
  u16* Vt  = (u16*)(ws + 56623104);   // 16 MB: [B,H,64,1024]
  // total 70 MB

  cvt_f32_bf16<<<8192, 256, 0, stream>>>(x, xb, 2097152);          // x -> bf16
  transpose_w_kernel<<<768, 256, 0, stream>>>(Wq, Wk, Wv, Wt);     // W -> Wt bf16
  gemm_bt<3072, 0><<<64 * 24, 256, 0, stream>>>(xb, Wt, Qb, Kb, Vt, nullptr, nullptr);
  cvt_f32_bf16<<<1024, 256, 0, stream>>>(Wp, Wpb, 262144);         // Wp -> bf16 (after Wt dead)
  attn_fwd<<<128 * 16, 256, 0, stream>>>(Qb, Kb, Vt, Ob);          // Ob overlays xb (xb dead)
  gemm_bt<1024, 1><<<64 * 8, 256, 0, stream>>>(Ob, Wpb, nullptr, nullptr, nullptr, out, bp);
}

// Round 3
// 216.967 us; speedup vs baseline: 1.6898x; 1.6898x over previous
//
#include <hip/hip_runtime.h>
#include <cstdint>

typedef unsigned short u16;
typedef short bf16x8 __attribute__((ext_vector_type(8)));
typedef float f32x4 __attribute__((ext_vector_type(4)));

__device__ __forceinline__ u16 f2bf(float f) {
  unsigned u = __builtin_bit_cast(unsigned, f);
  u = (u + 0x7fffu + ((u >> 16) & 1u)) >> 16;
  return (u16)u;
}

// async global->LDS, 16B per lane. LDS dst = wave-uniform base (HW adds lane*16);
// global src is per-lane.
__device__ __forceinline__ void gload_lds16(const void* g, void* l) {
  __builtin_amdgcn_global_load_lds(
      (const __attribute__((address_space(1))) unsigned int*)g,
      (__attribute__((address_space(3))) unsigned int*)l, 16, 0, 0);
}

// ---------------- Kernel 0: fp32 -> bf16 elementwise ------------------------
__global__ void cvt_f32_bf16(const float* __restrict__ src, u16* __restrict__ dst, int n4) {
  int i = blockIdx.x * 256 + threadIdx.x;
  if (i < n4) {
    float4 v = *reinterpret_cast<const float4*>(src + (size_t)i * 4);
    u16* d = dst + (size_t)i * 4;
    d[0] = f2bf(v.x); d[1] = f2bf(v.y); d[2] = f2bf(v.z); d[3] = f2bf(v.w);
  }
}

// ---------------- Kernel 1: weight transpose (fp32 in, bf16 out) ------------
// Wq/Wk/Wv: [16][1024][64] f32 -> Wt: [3072][1024] bf16 (row n = p*1024+h*64+d, col e)
__global__ void transpose_w_kernel(const float* __restrict__ Wq, const float* __restrict__ Wk,
                                   const float* __restrict__ Wv, u16* __restrict__ Wt) {
  __shared__ u16 tile[64][72];
  const int bid = blockIdx.x;
  const int et = bid & 15;
  const int h  = (bid >> 4) & 15;
  const int p  = bid >> 8;
  const float* W = (p == 0) ? Wq : ((p == 1) ? Wk : Wv);
  const int tid = threadIdx.x;
  for (int idx = tid; idx < 4096; idx += 256) {
    int i = idx >> 6, d = idx & 63;
    tile[d][i] = f2bf(W[(size_t)(h * 1024 + et * 64 + i) * 64 + d]);
  }
  __syncthreads();
  for (int idx = tid; idx < 4096; idx += 256) {
    int dd = idx >> 6, i = idx & 63;
    Wt[(size_t)(p * 1024 + h * 64 + dd) * 1024 + et * 64 + i] = tile[dd][i];
  }
}

// ---------------- Kernel 2/4: GEMM  C[M,N] = A[M,K] * Bt[N,K]^T -------------
template <int N, int MODE>
__global__ __launch_bounds__(256, 2)
void gemm_bt(const u16* __restrict__ A, const u16* __restrict__ Bt,
             u16* __restrict__ O0, u16* __restrict__ O1, u16* __restrict__ O2,
             float* __restrict__ Of, const float* __restrict__ bias) {
  constexpr int K = 1024, BM = 128, BK = 64;
  __shared__ u16 Asm[BM * BK];
  __shared__ u16 Bsm[BM * BK];
  const int tid = threadIdx.x;
  const int lane = tid & 63;
  const int wid = tid >> 6;
  constexpr int nbn = N / 128;
  const int bid = blockIdx.x;
  const int m0 = (bid / nbn) * 128, n0 = (bid % nbn) * 128;
  const int wm = (wid >> 1) * 64, wn = (wid & 1) * 64;
  const int fr = lane & 15;
  const int fk = (lane >> 4) << 3;

  f32x4 acc[4][4];
#pragma unroll
  for (int i = 0; i < 4; ++i)
#pragma unroll
    for (int j = 0; j < 4; ++j) acc[i][j] = f32x4{0.f, 0.f, 0.f, 0.f};

  for (int k0 = 0; k0 < K; k0 += BK) {
#pragma unroll
    for (int i = 0; i < 4; ++i) {
      int cbase = i * 256 + wid * 64;
      int chunk = cbase + lane;
      int row = chunk >> 3;
      int cole = (chunk & 7) << 3;
      gload_lds16(A + (size_t)(m0 + row) * K + k0 + cole, (char*)Asm + cbase * 16);
      gload_lds16(Bt + (size_t)(n0 + row) * K + k0 + cole, (char*)Bsm + cbase * 16);
    }
    __syncthreads();
#pragma unroll
    for (int kk = 0; kk < 2; ++kk) {
      bf16x8 af[4], bf[4];
#pragma unroll
      for (int mi = 0; mi < 4; ++mi)
        af[mi] = *reinterpret_cast<const bf16x8*>(&Asm[(wm + mi * 16 + fr) * BK + kk * 32 + fk]);
#pragma unroll
      for (int ni = 0; ni < 4; ++ni)
        bf[ni] = *reinterpret_cast<const bf16x8*>(&Bsm[(wn + ni * 16 + fr) * BK + kk * 32 + fk]);
#pragma unroll
      for (int mi = 0; mi < 4; ++mi)
#pragma unroll
        for (int ni = 0; ni < 4; ++ni)
          acc[mi][ni] = __builtin_amdgcn_mfma_f32_16x16x32_bf16(af[mi], bf[ni], acc[mi][ni], 0, 0, 0);
    }
    __syncthreads();
  }

  const int rq = (lane >> 4) << 2;
  if constexpr (MODE == 0) {
#pragma unroll
    for (int ni = 0; ni < 4; ++ni) {
      int n = n0 + wn + ni * 16 + fr;
      int pr = n >> 10, hh = (n >> 6) & 15, d = n & 63;
#pragma unroll
      for (int mi = 0; mi < 4; ++mi)
#pragma unroll
        for (int r = 0; r < 4; ++r) {
          int m = m0 + wm + mi * 16 + rq + r;
          int b = m >> 10, t = m & 1023;
          u16 val = f2bf(acc[mi][ni][r]);
          size_t bh = (size_t)(b * 16 + hh);
          if (pr == 0)      O0[(bh * 1024 + t) * 64 + d] = val;       // Q [B,H,T,64]
          else if (pr == 1) O1[(bh * 1024 + t) * 64 + d] = val;       // K [B,H,T,64]
          else              O2[(bh * 64 + d) * 1024 + t] = val;       // V^T [B,H,64,T]
        }
    }
  } else {
#pragma unroll
    for (int ni = 0; ni < 4; ++ni) {
      int n = n0 + wn + ni * 16 + fr;
      float bv = bias[n];
#pragma unroll
      for (int mi = 0; mi < 4; ++mi)
#pragma unroll
        for (int r = 0; r < 4; ++r) {
          int m = m0 + wm + mi * 16 + rq + r;
          Of[(size_t)m * N + n] = acc[mi][ni][r] + bv;
        }
    }
  }
}

// ---------------- Kernel 3: causal flash attention (v2) ----------------------
// Q,K: [B*H][1024][64] bf16, V: [B*H][64][1024] bf16, O: [B][1024][1024] bf16
// Grid: bid = c*128 + bh, c = 7-(bid>>7) descending-work; head->XCD affinity
// (bid%8 == bh%8). Block = 4 waves, NO barriers; wave w owns 32 q-rows
// (2x16 frags) at q0w = c*128 + w*32; per-wave KV loop bound.
__global__ __launch_bounds__(256, 2)
void attn_fwd(const u16* __restrict__ Q, const u16* __restrict__ K,
              const u16* __restrict__ V, u16* __restrict__ O) {
  __shared__ u16 Pl[4][2048];  // per-wave 2 frags x (16x64) bf16, XOR-swizzled
  const int tid = threadIdx.x, lane = tid & 63, w = tid >> 6;
  const int bid = blockIdx.x;
  const int bh = bid & 127;
  const int c  = 7 - (bid >> 7);
  const int b = bh >> 4, h = bh & 15;
  const int q0w = c * 128 + w * 32;
  const int fr = lane & 15, fg = lane >> 4, fk = fg << 3;
  const u16* Qb = Q + (size_t)bh * 65536;
  const u16* Kb = K + (size_t)bh * 65536;
  const u16* Vb = V + (size_t)bh * 65536;
  char* Pw = (char*)&Pl[w][0];  // 4KB per wave

  bf16x8 qf[2][2];
#pragma unroll
  for (int qm = 0; qm < 2; ++qm)
#pragma unroll
    for (int kk = 0; kk < 2; ++kk)
      qf[qm][kk] = *reinterpret_cast<const bf16x8*>(&Qb[(q0w + qm * 16 + fr) * 64 + kk * 32 + fk]);

  f32x4 o[2][4];
  float mrow[2][4], lrow[2][4];
#pragma unroll
  for (int qm = 0; qm < 2; ++qm)
#pragma unroll
    for (int i = 0; i < 4; ++i) {
      o[qm][i] = f32x4{0.f, 0.f, 0.f, 0.f};
      mrow[qm][i] = -1e30f; lrow[qm][i] = 0.f;
    }
  const float cst = 0.125f * 1.44269504088896f;  // hs^-0.5 * log2(e)

  const int stmax = (q0w + 31) >> 6;  // inclusive per-wave bound
  for (int st = 0; st <= stmax; ++st) {
    const u16* Kt = Kb + st * 4096;
    f32x4 s[2][4];
#pragma unroll
    for (int qm = 0; qm < 2; ++qm)
#pragma unroll
      for (int i = 0; i < 4; ++i) s[qm][i] = f32x4{0.f, 0.f, 0.f, 0.f};
#pragma unroll
    for (int kk = 0; kk < 2; ++kk)
#pragma unroll
      for (int nf = 0; nf < 4; ++nf) {
        bf16x8 kf = *reinterpret_cast<const bf16x8*>(&Kt[(nf * 16 + fr) * 64 + kk * 32 + fk]);
        s[0][nf] = __builtin_amdgcn_mfma_f32_16x16x32_bf16(qf[0][kk], kf, s[0][nf], 0, 0, 0);
        s[1][nf] = __builtin_amdgcn_mfma_f32_16x16x32_bf16(qf[1][kk], kf, s[1][nf], 0, 0, 0);
      }

#pragma unroll
    for (int qm = 0; qm < 2; ++qm) {
      const int qb = q0w + qm * 16;
      const bool need_mask = (st * 64 + 63 > qb);  // wave-uniform
      float sv[4][4];
#pragma unroll
      for (int nf = 0; nf < 4; ++nf)
#pragma unroll
        for (int r = 0; r < 4; ++r) {
          float xv = s[qm][nf][r] * cst;
          if (need_mask) {
            int sc = st * 64 + nf * 16 + fr;
            int qr = qb + fg * 4 + r;
            if (sc > qr) xv = -1e30f;
          }
          sv[nf][r] = xv;
        }
      char* Pq = Pw + qm * 2048;
#pragma unroll
      for (int r = 0; r < 4; ++r) {
        float mx = fmaxf(fmaxf(sv[0][r], sv[1][r]), fmaxf(sv[2][r], sv[3][r]));
        mx = fmaxf(mx, __shfl_xor(mx, 1));
        mx = fmaxf(mx, __shfl_xor(mx, 2));
        mx = fmaxf(mx, __shfl_xor(mx, 4));
        mx = fmaxf(mx, __shfl_xor(mx, 8));
        float mnew = fmaxf(mrow[qm][r], mx);
        float a = exp2f(mrow[qm][r] - mnew);
        lrow[qm][r] *= a;
        o[qm][0][r] *= a; o[qm][1][r] *= a; o[qm][2][r] *= a; o[qm][3][r] *= a;
        mrow[qm][r] = mnew;
        float sum = 0.f;
#pragma unroll
        for (int nf = 0; nf < 4; ++nf) {
          float pv = exp2f(sv[nf][r] - mnew);
          sum += pv;
          int mm = fg * 4 + r, nn = nf * 16 + fr;
          int byteoff = (mm * 128 + nn * 2) ^ ((mm & 7) << 4);
          *(u16*)(Pq + byteoff) = f2bf(pv);
        }
        sum += __shfl_xor(sum, 1);
        sum += __shfl_xor(sum, 2);
        sum += __shfl_xor(sum, 4);
        sum += __shfl_xor(sum, 8);
        lrow[qm][r] += sum;
      }
    }

    // PV: same-wave LDS write->read is in-order; no barrier needed.
#pragma unroll
    for (int kk = 0; kk < 2; ++kk) {
      int rb = (fr * 128 + kk * 64 + fg * 16) ^ ((fr & 7) << 4);
      bf16x8 pa0 = *reinterpret_cast<const bf16x8*>(Pw + rb);
      bf16x8 pa1 = *reinterpret_cast<const bf16x8*>(Pw + 2048 + rb);
#pragma unroll
      for (int df = 0; df < 4; ++df) {
        bf16x8 vf = *reinterpret_cast<const bf16x8*>(&Vb[(df * 16 + fr) * 1024 + st * 64 + kk * 32 + fk]);
        o[0][df] = __builtin_amdgcn_mfma_f32_16x16x32_bf16(pa0, vf, o[0][df], 0, 0, 0);
        o[1][df] = __builtin_amdgcn_mfma_f32_16x16x32_bf16(pa1, vf, o[1][df], 0, 0, 0);
      }
    }
  }

#pragma unroll
  for (int qm = 0; qm < 2; ++qm)
#pragma unroll
    for (int r = 0; r < 4; ++r) {
      float inv = 1.0f / lrow[qm][r];
      int t = q0w + qm * 16 + fg * 4 + r;
      size_t base = ((size_t)b * 1024 + t) * 1024 + h * 64;
#pragma unroll
      for (int df = 0; df < 4; ++df) O[base + df * 16 + fr] = f2bf(o[qm][df][r] * inv);
    }
}

// ---------------- launcher ---------------------------------------------------
extern "C" void kernel_launch(void* const* d_in, const int* in_sizes, int n_in,
                              void* d_out, int out_size, void* d_ws, size_t ws_size,
                              hipStream_t stream) {
  (void)in_sizes; (void)n_in; (void)out_size; (void)ws_size;
  const float* x  = (const float*)d_in[0];
  const float* Wq = (const float*)d_in[1];
  const float* Wk = (const float*)d_in[2];
  const float* Wv = (const float*)d_in[3];
  const float* Wp = (const float*)d_in[4];
  const float* bp = (const float*)d_in[5];
  float* out = (float*)d_out;

  char* ws = (char*)d_ws;
  u16* xb  = (u16*)(ws);              // 16MB, reused as Ob after attn input dead
  u16* Ob  = (u16*)(ws);
  u16* Wt  = (u16*)(ws + 16777216);   // 6MB, reused as Wpb
  u16* Wpb = (u16*)(ws + 16777216);
  u16* Qb  = (u16*)(ws + 23068672);   // 16 MB: [B,H,1024,64]
  u16* Kb  = (u16*)(ws + 39845888);   // 16 MB
  u16* Vt  = (u16*)(ws + 56623104);   // 16 MB: [B,H,64,1024]

  cvt_f32_bf16<<<8192, 256, 0, stream>>>(x, xb, 2097152);
  transpose_w_kernel<<<768, 256, 0, stream>>>(Wq, Wk, Wv, Wt);
  gemm_bt<3072, 0><<<64 * 24, 256, 0, stream>>>(xb, Wt, Qb, Kb, Vt, nullptr, nullptr);
  cvt_f32_bf16<<<1024, 256, 0, stream>>>(Wp, Wpb, 262144);
  attn_fwd<<<1024, 256, 0, stream>>>(Qb, Kb, Vt, Ob);
  gemm_bt<1024, 1><<<64 * 8, 256, 0, stream>>>(Ob, Wpb, nullptr, nullptr, nullptr, out, bp);
}